// Round 6
// baseline (399.510 us; speedup 1.0000x reference)
//
#include <hip/hip_runtime.h>
#include <math.h>

// Problem constants
#define NF 5
#define NB 8
#define NC 64
#define HW 16384
#define NK 320               // NF*NC
#define FSTRIDE (NB*NC*HW)   // elements per frame = 8388608

// ws layout (floats)
#define EN_FLOATS    (NB*NC*8)   // 4096
#define ALPHA_FLOATS (NB*NK)     // 2560
#define WT_FLOATS    (NK*NC)     // 20480
#define PART_FLOATS  (8*NB*HW)   // 1048576 (4 MB) for k3 partials

// ---------------- k0: transpose origin_w [64][320] -> Wt [320][64] ----------------
__global__ void k0_wt(const float* __restrict__ W, float* __restrict__ Wt){
    int idx = blockIdx.x*256 + threadIdx.x;
    if (idx < NC*NK){
        int c = idx / NK;
        int k = idx - c*NK;
        Wt[k*NC + c] = W[idx];
    }
}

// ---------------- k1: fused GEMM + E/N — scalar-pipe W, no LDS in k-loop ----------
// Block = 256 thr = (channel-octet cg, batch b, 512-spatial chunk sc), all from
// blockIdx -> W addresses are BLOCK-uniform -> s_load (scalar pipe). Round 5's
// k-loop issued 2 ds_read_b128 broadcasts/k/wave = ~102 us of LDS-pipe time/CU;
// this moves W entirely off the LDS pipe. Thread = 8 ch x 2 sp = 16 accs
// (round 5's proven VGPR=40 shape, no spill).
// Grid order: cg slowest -> the 8 blocks sharing an X slice are 256 apart
// (256%8==0 -> same XCD) so L2 serves the 8x channel-octet redundancy.
// Phase B: o transposed via 17 KB LDS (one-shot), thread=(c,i,schunk) sums 64
// spatial from L1/L2-hot X rows, shfl-combine over schunk, atomicAdd EN.
__global__ __launch_bounds__(256) void k1_fused(
    const float* __restrict__ inp, const float* __restrict__ Wt,
    const float* __restrict__ bias, float* __restrict__ EN)
{
    __shared__ float Ol[8*8*68];        // [c][schunk][68] = 17408 B

    const int tid = threadIdx.x;
    const int cg  = blockIdx.x >> 8;        // 0..7  (slowest)
    const int b   = (blockIdx.x >> 5) & 7;  // 0..7
    const int sc  = blockIdx.x & 31;        // 0..31 (fastest)
    const int c0  = cg << 3;
    const int s0  = sc << 9;                // 512-wide spatial window
    const int sp  = tid << 1;               // thread's 2 spatial positions

    // ---- Phase A: 8 channels x 2 spatial accumulators ----
    float2 a0,a1,a2,a3,a4,a5,a6,a7;
    {
        float4 b0 = *reinterpret_cast<const float4*>(bias + c0);
        float4 b1 = *reinterpret_cast<const float4*>(bias + c0 + 4);
        a0 = make_float2(b0.x,b0.x); a1 = make_float2(b0.y,b0.y);
        a2 = make_float2(b0.z,b0.z); a3 = make_float2(b0.w,b0.w);
        a4 = make_float2(b1.x,b1.x); a5 = make_float2(b1.y,b1.y);
        a6 = make_float2(b1.z,b1.z); a7 = make_float2(b1.w,b1.w);
    }

#pragma unroll 1
    for (int f=0; f<NF; ++f){
        const float* xp = inp + ((size_t)(f*NB + b)*NC)*HW + s0 + sp;
        const float* wp = Wt + f*(NC*NC) + c0;     // block-uniform -> s_load
#pragma unroll 4
        for (int k=0; k<64; ++k){
            float2 xv = *reinterpret_cast<const float2*>(xp);
            xp += HW;
            float4 wA = *reinterpret_cast<const float4*>(wp);      // s_load_dwordx4
            float4 wB = *reinterpret_cast<const float4*>(wp + 4);  // s_load_dwordx4
            wp += NC;
            a0.x = fmaf(wA.x, xv.x, a0.x); a0.y = fmaf(wA.x, xv.y, a0.y);
            a1.x = fmaf(wA.y, xv.x, a1.x); a1.y = fmaf(wA.y, xv.y, a1.y);
            a2.x = fmaf(wA.z, xv.x, a2.x); a2.y = fmaf(wA.z, xv.y, a2.y);
            a3.x = fmaf(wA.w, xv.x, a3.x); a3.y = fmaf(wA.w, xv.y, a3.y);
            a4.x = fmaf(wB.x, xv.x, a4.x); a4.y = fmaf(wB.x, xv.y, a4.y);
            a5.x = fmaf(wB.y, xv.x, a5.x); a5.y = fmaf(wB.y, xv.y, a5.y);
            a6.x = fmaf(wB.z, xv.x, a6.x); a6.y = fmaf(wB.z, xv.y, a6.y);
            a7.x = fmaf(wB.w, xv.x, a7.x); a7.y = fmaf(wB.w, xv.y, a7.y);
        }
    }

    // ---- dump o to LDS: Ol[c][sp>>6][sp&63] ----
    {
        float* od = Ol + ((sp >> 6) * 68) + (sp & 63);
        *reinterpret_cast<float2*>(od + 0*544) = a0;
        *reinterpret_cast<float2*>(od + 1*544) = a1;
        *reinterpret_cast<float2*>(od + 2*544) = a2;
        *reinterpret_cast<float2*>(od + 3*544) = a3;
        *reinterpret_cast<float2*>(od + 4*544) = a4;
        *reinterpret_cast<float2*>(od + 5*544) = a5;
        *reinterpret_cast<float2*>(od + 6*544) = a6;
        *reinterpret_cast<float2*>(od + 7*544) = a7;
    }
    __syncthreads();

    // ---- Phase B: thread = (pc = c-local, pi = frame, ps = 64-wide schunk) ----
    const int pc = tid >> 5;          // 0..7
    const int pi = (tid >> 3) & 3;    // 0..3
    const int ps = tid & 7;           // 0..7
    const float* orow = Ol + pc*544 + ps*68;
    const size_t rowoff = ((size_t)b*NC + c0 + pc)*HW + s0 + (ps << 6);
    const float* x4r = inp + (size_t)4*FSTRIDE + rowoff;
    const float* xir = inp + (size_t)pi*FSTRIDE + rowoff;
    float e = 0.f, n = 0.f;
#pragma unroll 4
    for (int j=0; j<16; ++j){
        float4 ov = *reinterpret_cast<const float4*>(orow + 4*j);
        float4 x4 = *reinterpret_cast<const float4*>(x4r  + 4*j);
        float4 xi = *reinterpret_cast<const float4*>(xir  + 4*j);
        float d0 = x4.x - xi.x, d1 = x4.y - xi.y;
        float d2 = x4.z - xi.z, d3 = x4.w - xi.w;
        n = fmaf(d0,d0, fmaf(d1,d1, fmaf(d2,d2, fmaf(d3,d3, n))));
        e = fmaf(ov.x,d0, fmaf(ov.y,d1, fmaf(ov.z,d2, fmaf(ov.w,d3, e))));
    }
    // combine the 8 schunks (consecutive lanes, bits 0..2)
    e += __shfl_xor(e, 1, 64); e += __shfl_xor(e, 2, 64); e += __shfl_xor(e, 4, 64);
    n += __shfl_xor(n, 1, 64); n += __shfl_xor(n, 2, 64); n += __shfl_xor(n, 4, 64);
    if (ps == 0){
        float* enb = EN + ((size_t)b*NC + c0 + pc)*8;
        atomicAdd(&enb[pi],     e);
        atomicAdd(&enb[4 + pi], n);
    }
}

// ---------------- k2: finalize coef -> alpha ----------------
__global__ void k2_coef(const float* __restrict__ EN, const float* __restrict__ out_w,
                        float* __restrict__ alpha)
{
    int tid = threadIdx.x;          // 512 = NB*NC
    int b = tid >> 6, c = tid & 63;
    const float* e = EN + (b*NC + c)*8;
    float w1 = out_w[c], w2 = out_w[NC + c];
    float csum = 0.f;
#pragma unroll
    for (int i=0; i<4; ++i){
        float nc = fmaxf(sqrtf(e[4+i]), 1e-12f);
        float coef = e[i] / (nc*nc);
        alpha[b*NK + i*NC + c] = -w1*coef;
        csum += coef;
    }
    alpha[b*NK + 4*NC + c] = w1*csum + w2;
}

// ---------------- k3a: partial matvec, 8-way split over rows ----------------
// 1024 blocks x 256 thr (16 waves/CU). Thread = 4 consecutive s (float4,
// 16B/lane); group g sums rows 40g..40g+39. alpha uniform -> s_load.
__global__ __launch_bounds__(256) void k3_partial(const float* __restrict__ inp,
        const float* __restrict__ alpha, float* __restrict__ part)
{
    const int g  = blockIdx.x >> 7;        // 0..7
    const int b  = (blockIdx.x >> 4) & 7;  // 0..7
    const int sc = blockIdx.x & 15;        // 0..15
    const int s  = (sc << 10) + (threadIdx.x << 2);
    const float* al = alpha + b*NK;        // uniform -> s_load
    float4 acc = make_float4(0.f, 0.f, 0.f, 0.f);
    const int r0 = g*40;
#pragma unroll 8
    for (int rr=0; rr<40; ++rr){
        int r = r0 + rr;
        int f = r >> 6, c = r & 63;
        float4 xv = *reinterpret_cast<const float4*>(
            inp + ((size_t)(f*NB + b)*NC + c)*HW + s);
        float w = al[r];
        acc.x = fmaf(w, xv.x, acc.x); acc.y = fmaf(w, xv.y, acc.y);
        acc.z = fmaf(w, xv.z, acc.z); acc.w = fmaf(w, xv.w, acc.w);
    }
    *reinterpret_cast<float4*>(part + ((size_t)g*NB + b)*HW + s) = acc;
}

// ---------------- k3b: combine partials + bias ----------------
__global__ __launch_bounds__(256) void k3_combine(const float* __restrict__ part,
        const float* __restrict__ out_b, float* __restrict__ y)
{
    int j = (blockIdx.x*256 + threadIdx.x) << 2;   // 128 blocks cover 131072
    float bb = out_b[0];
    float4 acc = make_float4(bb, bb, bb, bb);
#pragma unroll
    for (int g=0; g<8; ++g){
        float4 p = *reinterpret_cast<const float4*>(part + (size_t)g*NB*HW + j);
        acc.x += p.x; acc.y += p.y; acc.z += p.z; acc.w += p.w;
    }
    *reinterpret_cast<float4*>(y + j) = acc;
}

// ---------------- k3 fallback (small ws): monolithic ----------------
__global__ __launch_bounds__(256) void k3_mono(const float* __restrict__ inp,
        const float* __restrict__ alpha, const float* __restrict__ out_b,
        float* __restrict__ y)
{
    const int b  = blockIdx.x >> 4;
    const int s  = ((blockIdx.x & 15) << 10) + (threadIdx.x << 2);
    const float* al = alpha + b*NK;
    float bb = out_b[0];
    float4 acc = make_float4(bb, bb, bb, bb);
#pragma unroll 8
    for (int r=0; r<NK; ++r){
        int f = r >> 6, c = r & 63;
        float4 xv = *reinterpret_cast<const float4*>(
            inp + ((size_t)(f*NB + b)*NC + c)*HW + s);
        float w = al[r];
        acc.x = fmaf(w, xv.x, acc.x); acc.y = fmaf(w, xv.y, acc.y);
        acc.z = fmaf(w, xv.z, acc.z); acc.w = fmaf(w, xv.w, acc.w);
    }
    *reinterpret_cast<float4*>(y + (size_t)b*HW + s) = acc;
}

extern "C" void kernel_launch(void* const* d_in, const int* in_sizes, int n_in,
                              void* d_out, int out_size, void* d_ws, size_t ws_size,
                              hipStream_t stream)
{
    const float* inp      = (const float*)d_in[0];
    const float* origin_w = (const float*)d_in[1];
    const float* origin_b = (const float*)d_in[2];
    const float* out_w    = (const float*)d_in[3];
    const float* out_b    = (const float*)d_in[4];
    float* y  = (float*)d_out;
    float* ws = (float*)d_ws;

    float* EN    = ws;                                          // 4096
    float* alpha = ws + EN_FLOATS;                              // 2560
    float* Wt    = ws + EN_FLOATS + ALPHA_FLOATS;               // 20480
    float* part  = ws + EN_FLOATS + ALPHA_FLOATS + WT_FLOATS;   // 1048576

    const size_t need = (size_t)(EN_FLOATS + ALPHA_FLOATS + WT_FLOATS + PART_FLOATS)
                        * sizeof(float);

    hipMemsetAsync(EN, 0, EN_FLOATS*sizeof(float), stream);
    k0_wt   <<<(NC*NK + 255)/256, 256, 0, stream>>>(origin_w, Wt);
    k1_fused<<<2048, 256, 0, stream>>>(inp, Wt, origin_b, EN);
    k2_coef <<<1, NB*NC, 0, stream>>>(EN, out_w, alpha);
    if (ws_size >= need){
        k3_partial<<<1024, 256, 0, stream>>>(inp, alpha, part);
        k3_combine<<<128, 256, 0, stream>>>(part, out_b, y);
    } else {
        k3_mono<<<128, 256, 0, stream>>>(inp, alpha, out_b, y);
    }
}